// Round 6
// baseline (214.211 us; speedup 1.0000x reference)
//
#include <hip/hip_runtime.h>
#include <cstdint>
#include <cstddef>

// ConcreteLayer forward: out = x @ softmax_rows((W + gumbel(U))/T)
// Reformulated: d_k = sum_n exp(l_kn);  out = (x .* (1/d)[k]) @ exp(l)
// B=4096, IN=4096, OUT=1024. bf16 MFMA GEMM; x cast+scale fused into GEMM staging.
// ws: bt (bf16 exp(l)^T [OUT,IN], 8MB) | d (4096 f32 row sums)

#define TINYF 1.17549435082228750797e-38f
#define LN2F 0.69314718055994530942f
#define LOG2EF 1.44269504088896340736f

typedef unsigned short u16;
typedef __attribute__((ext_vector_type(8))) short bf16x8;
typedef __attribute__((ext_vector_type(4))) float f32x4;

__device__ __forceinline__ u16 f2bf(float f) {
  union { float f; uint32_t u; } v; v.f = f;
  uint32_t r = v.u + 0x7FFFu + ((v.u >> 16) & 1u);  // RNE
  return (u16)(r >> 16);
}

__device__ __forceinline__ float log2_hw(float x) { return __builtin_amdgcn_logf(x); }
__device__ __forceinline__ float exp2_hw(float x) { return __builtin_amdgcn_exp2f(x); }
__device__ __forceinline__ float rcp_hw(float x) { return __builtin_amdgcn_rcpf(x); }

// g = -ln(-ln(u)) = -ln2 * log2(ln2 * (-log2 u))
__device__ __forceinline__ float gumbel_fast(float u) {
  float t = -log2_hw(u);
  return -LN2F * log2_hw(t * LN2F);
}
__device__ __forceinline__ float exp_fast(float x) { return exp2_hw(x * LOG2EF); }

__device__ __forceinline__ void gld_lds16(const void* g, void* l) {
  __builtin_amdgcn_global_load_lds(
      (__attribute__((address_space(1))) void*)(g),
      (__attribute__((address_space(3))) void*)(l), 16, 0, 0);
}

// ---------------- kernel 1: exp-transpose + row-sum accumulate + zero-init of out ----------------
__global__ void trans_exp_kernel(const float* __restrict__ W, const float* __restrict__ U,
                                 const float* __restrict__ Tp, u16* __restrict__ BT,
                                 float* __restrict__ d, float4* __restrict__ out4) {
  __shared__ float tile[64][65];
  const int k0 = blockIdx.x * 64, n0 = blockIdx.y * 64;
  const int t = threadIdx.x;
  const float invT = 1.0f / Tp[0];

  // fused zero-init of d_out: 1024 blocks x 1024 float4
  {
    int bid = blockIdx.y * gridDim.x + blockIdx.x;
    float4 z = make_float4(0.f, 0.f, 0.f, 0.f);
#pragma unroll
    for (int j = 0; j < 4; ++j) out4[(size_t)bid * 1024 + j * 256 + t] = z;
  }

  {
    const int nn4 = (t & 15) * 4, kq = t >> 4;   // 16 rows per pass, float4 cols
#pragma unroll
    for (int r = 0; r < 4; ++r) {
      int kk = r * 16 + kq;
      size_t gi = (size_t)(k0 + kk) * 1024 + (n0 + nn4);
      float4 w = *(const float4*)&W[gi];
      float4 u = *(const float4*)&U[gi];
      float e0 = exp_fast((w.x + gumbel_fast(u.x * (1.0f - TINYF) + TINYF)) * invT);
      float e1 = exp_fast((w.y + gumbel_fast(u.y * (1.0f - TINYF) + TINYF)) * invT);
      float e2 = exp_fast((w.z + gumbel_fast(u.z * (1.0f - TINYF) + TINYF)) * invT);
      float e3 = exp_fast((w.w + gumbel_fast(u.w * (1.0f - TINYF) + TINYF)) * invT);
      tile[kk][nn4 + 0] = e0; tile[kk][nn4 + 1] = e1;
      tile[kk][nn4 + 2] = e2; tile[kk][nn4 + 3] = e3;
      float s = (e0 + e1) + (e2 + e3);
#pragma unroll
      for (int m = 8; m > 0; m >>= 1) s += __shfl_xor(s, m, 16);
      if ((t & 15) == 0) atomicAdd(&d[k0 + kk], s);
    }
  }
  __syncthreads();
  {
    const int kk4 = (t & 15) * 4, nq = t >> 4;
#pragma unroll
    for (int r = 0; r < 4; ++r) {
      int nn = r * 16 + nq;
      ushort4 o;
      o.x = f2bf(tile[kk4 + 0][nn]);
      o.y = f2bf(tile[kk4 + 1][nn]);
      o.z = f2bf(tile[kk4 + 2][nn]);
      o.w = f2bf(tile[kk4 + 3][nn]);
      *(ushort4*)&BT[(size_t)(n0 + nn) * 4096 + (k0 + kk4)] = o;
    }
  }
}

// ---------------- kernel 2: GEMM, A staged fp32->(x/d)->bf16 in-register, B via gld_lds ----------------
// 128x128 tile, TK=64, XOR-swizzled LDS (slot = granule ^ (row&7)), split-K=4.
#define TM 128
#define TN 128
#define TK 64
#define SPLITK 4

__launch_bounds__(256, 3)
__global__ void gemm_fused_kernel(const float* __restrict__ X, const float* __restrict__ dsum,
                                  const u16* __restrict__ BT, float* __restrict__ C,
                                  int M, int N, int K) {
  __shared__ u16 As[TM * TK];  // 16 KB
  __shared__ u16 Bs[TN * TK];  // 16 KB

  const int tid = threadIdx.x;
  const int lane = tid & 63, w = tid >> 6;
  const int wm = w >> 1, wn = w & 1;           // 2x2 wave grid, 64x64 per wave
  const int m0 = blockIdx.x * TM, n0 = blockIdx.y * TN;
  const int quad = lane >> 4, r16 = lane & 15;
  // B staging (gld_lds, swizzled global source)
  const int srow = lane >> 3;
  const int sg = (lane & 7) ^ srow;
  // A staging (per-thread: one 8-elem granule of 4 rows)
  const int arow = tid >> 3;                   // 0..31
  const int gb = tid & 7;                      // k-granule (8 fp32)
  const int aslot = (gb ^ (arow & 7)) * 16;    // swizzled LDS byte slot (row&7 == arow&7)

  const int kz = blockIdx.z;
  const int Kq = K / SPLITK;                   // 1024
  const float* Xk = X + (size_t)kz * Kq;
  const u16* Bk = BT + (size_t)kz * Kq;
  const float* dk = dsum + (size_t)kz * Kq;

  f32x4 acc[4][4] = {};

  for (int kt = 0; kt < Kq; kt += TK) {
    __syncthreads();
    // A: 8 independent float4 loads first (their waitcnt leaves B's gld_lds in flight)
    float4 av[4][2];
#pragma unroll
    for (int p = 0; p < 4; ++p) {
      const float* src = Xk + (size_t)(m0 + p * 32 + arow) * K + kt + gb * 8;
      av[p][0] = *(const float4*)src;
      av[p][1] = *(const float4*)(src + 4);
    }
    // B: async global->LDS
#pragma unroll
    for (int c = 0; c < 4; ++c) {
      int chunk = w * 4 + c;
      gld_lds16(Bk + (size_t)(n0 + chunk * 8 + srow) * K + kt + sg * 8, (char*)Bs + chunk * 1024);
    }
    // 1/d for this thread's 8 k values (L1/L2-hot)
    float4 dv0 = *(const float4*)(dk + kt + gb * 8);
    float4 dv1 = *(const float4*)(dk + kt + gb * 8 + 4);
    float rd0x = rcp_hw(dv0.x), rd0y = rcp_hw(dv0.y), rd0z = rcp_hw(dv0.z), rd0w = rcp_hw(dv0.w);
    float rd1x = rcp_hw(dv1.x), rd1y = rcp_hw(dv1.y), rd1z = rcp_hw(dv1.z), rd1w = rcp_hw(dv1.w);
    // scale + cvt + swizzled ds_write_b128
#pragma unroll
    for (int p = 0; p < 4; ++p) {
      int row = p * 32 + arow;
      union { u16 u[8]; bf16x8 v; } pk;
      pk.u[0] = f2bf(av[p][0].x * rd0x);
      pk.u[1] = f2bf(av[p][0].y * rd0y);
      pk.u[2] = f2bf(av[p][0].z * rd0z);
      pk.u[3] = f2bf(av[p][0].w * rd0w);
      pk.u[4] = f2bf(av[p][1].x * rd1x);
      pk.u[5] = f2bf(av[p][1].y * rd1y);
      pk.u[6] = f2bf(av[p][1].z * rd1z);
      pk.u[7] = f2bf(av[p][1].w * rd1w);
      *(bf16x8*)((char*)As + row * 128 + aslot) = pk.v;
    }
    __syncthreads();

#pragma unroll
    for (int ss = 0; ss < 2; ++ss) {           // two K=32 sub-steps per staged TK=64
      bf16x8 aF[4], bF[4];
#pragma unroll
      for (int mi = 0; mi < 4; ++mi) {
        int row = wm * 64 + mi * 16 + r16;
        aF[mi] = *(const bf16x8*)((const char*)As + row * 128 + (((ss * 4 + quad) ^ (row & 7)) * 16));
      }
#pragma unroll
      for (int ni = 0; ni < 4; ++ni) {
        int row = wn * 64 + ni * 16 + r16;
        bF[ni] = *(const bf16x8*)((const char*)Bs + row * 128 + (((ss * 4 + quad) ^ (row & 7)) * 16));
      }
#pragma unroll
      for (int mi = 0; mi < 4; ++mi)
#pragma unroll
        for (int ni = 0; ni < 4; ++ni)
          acc[mi][ni] = __builtin_amdgcn_mfma_f32_16x16x32_bf16(aF[mi], bF[ni], acc[mi][ni], 0, 0, 0);
    }
  }

  // epilogue: C/D layout col = lane&15, row = quad*4 + reg; accumulate split-K partials
#pragma unroll
  for (int mi = 0; mi < 4; ++mi)
#pragma unroll
    for (int ni = 0; ni < 4; ++ni)
#pragma unroll
      for (int r = 0; r < 4; ++r) {
        int row = m0 + wm * 64 + mi * 16 + quad * 4 + r;
        int col = n0 + wn * 64 + ni * 16 + r16;
        atomicAdd(&C[(size_t)row * N + col], acc[mi][ni][r]);
      }
}

extern "C" void kernel_launch(void* const* d_in, const int* in_sizes, int n_in,
                              void* d_out, int out_size, void* d_ws, size_t ws_size,
                              hipStream_t stream) {
  const int M = 4096, K = 4096, N = 1024;  // B, IN, OUT
  const float* x = (const float*)d_in[0];
  const float* W = (const float*)d_in[1];
  const float* U = (const float*)d_in[2];
  const float* Tp = (const float*)d_in[3];
  float* out = (float*)d_out;

  char* ws = (char*)d_ws;
  u16* bt = (u16*)ws;                                   // 8 MB
  float* dsum = (float*)(ws + (size_t)N * K * 2);       // 16 KB

  hipMemsetAsync(dsum, 0, K * sizeof(float), stream);
  trans_exp_kernel<<<dim3(K / 64, N / 64), 256, 0, stream>>>(W, U, Tp, bt, dsum, (float4*)out);
  gemm_fused_kernel<<<dim3(M / TM, N / TN, SPLITK), 256, 0, stream>>>(x, dsum, bt, out, M, N, K);
}

// Round 7
// 212.364 us; speedup vs baseline: 1.0087x; 1.0087x over previous
//
#include <hip/hip_runtime.h>
#include <cstdint>
#include <cstddef>

// ConcreteLayer forward: out = x @ softmax_rows((W + gumbel(U))/T)
// Reformulated: d_k = sum_n exp(l_kn);  out = (x .* (1/d)[k]) @ exp(l)
// B=4096, IN=4096, OUT=1024. bf16 MFMA GEMM.
// ws: xb (bf16 x/d, 32MB) | bt (bf16 exp(l)^T [OUT,IN], 8MB) | d (4096 f32)

#define TINYF 1.17549435082228750797e-38f
#define LN2F 0.69314718055994530942f
#define LOG2EF 1.44269504088896340736f

typedef unsigned short u16;
typedef __attribute__((ext_vector_type(8))) short bf16x8;
typedef __attribute__((ext_vector_type(4))) float f32x4;

__device__ __forceinline__ u16 f2bf(float f) {
  union { float f; uint32_t u; } v; v.f = f;
  uint32_t r = v.u + 0x7FFFu + ((v.u >> 16) & 1u);  // RNE
  return (u16)(r >> 16);
}

__device__ __forceinline__ float log2_hw(float x) { return __builtin_amdgcn_logf(x); }
__device__ __forceinline__ float exp2_hw(float x) { return __builtin_amdgcn_exp2f(x); }
__device__ __forceinline__ float rcp_hw(float x) { return __builtin_amdgcn_rcpf(x); }

// g = -ln(-ln(u)) = -ln2 * log2(ln2 * (-log2 u))
__device__ __forceinline__ float gumbel_fast(float u) {
  float t = -log2_hw(u);
  return -LN2F * log2_hw(t * LN2F);
}
__device__ __forceinline__ float exp_fast(float x) { return exp2_hw(x * LOG2EF); }

__device__ __forceinline__ void gld_lds16(const void* g, void* l) {
  __builtin_amdgcn_global_load_lds(
      (__attribute__((address_space(1))) void*)(g),
      (__attribute__((address_space(3))) void*)(l), 16, 0, 0);
}

// ---------------- kernel 1: exp-transpose + row-sum accumulate + zero-init of out ----------------
__global__ void trans_exp_kernel(const float* __restrict__ W, const float* __restrict__ U,
                                 const float* __restrict__ Tp, u16* __restrict__ BT,
                                 float* __restrict__ d, float4* __restrict__ out4) {
  __shared__ float tile[64][65];
  const int k0 = blockIdx.x * 64, n0 = blockIdx.y * 64;
  const int t = threadIdx.x;
  const float invT = 1.0f / Tp[0];

  // fused zero-init of d_out: 1024 blocks x 4 KB
  {
    int bid = blockIdx.y * gridDim.x + blockIdx.x;
    float4 z = make_float4(0.f, 0.f, 0.f, 0.f);
#pragma unroll
    for (int j = 0; j < 4; ++j) out4[(size_t)bid * 1024 + j * 256 + t] = z;
  }

  {
    const int nn4 = (t & 15) * 4, kq = t >> 4;   // 16 rows per pass, float4 cols
#pragma unroll
    for (int r = 0; r < 4; ++r) {
      int kk = r * 16 + kq;
      size_t gi = (size_t)(k0 + kk) * 1024 + (n0 + nn4);
      float4 w = *(const float4*)&W[gi];
      float4 u = *(const float4*)&U[gi];
      float e0 = exp_fast((w.x + gumbel_fast(u.x * (1.0f - TINYF) + TINYF)) * invT);
      float e1 = exp_fast((w.y + gumbel_fast(u.y * (1.0f - TINYF) + TINYF)) * invT);
      float e2 = exp_fast((w.z + gumbel_fast(u.z * (1.0f - TINYF) + TINYF)) * invT);
      float e3 = exp_fast((w.w + gumbel_fast(u.w * (1.0f - TINYF) + TINYF)) * invT);
      tile[kk][nn4 + 0] = e0; tile[kk][nn4 + 1] = e1;
      tile[kk][nn4 + 2] = e2; tile[kk][nn4 + 3] = e3;
      float s = (e0 + e1) + (e2 + e3);
#pragma unroll
      for (int m = 8; m > 0; m >>= 1) s += __shfl_xor(s, m, 16);
      if ((t & 15) == 0) atomicAdd(&d[k0 + kk], s);
    }
  }
  __syncthreads();
  {
    const int kk4 = (t & 15) * 4, nq = t >> 4;
#pragma unroll
    for (int r = 0; r < 4; ++r) {
      int nn = r * 16 + nq;
      ushort4 o;
      o.x = f2bf(tile[kk4 + 0][nn]);
      o.y = f2bf(tile[kk4 + 1][nn]);
      o.z = f2bf(tile[kk4 + 2][nn]);
      o.w = f2bf(tile[kk4 + 3][nn]);
      *(ushort4*)&BT[(size_t)(n0 + nn) * 4096 + (k0 + kk4)] = o;
    }
  }
}

// ---------------- kernel 2: xb = bf16(x * rcp(d)) ----------------
__global__ void cast_kernel(const float4* __restrict__ x, const float4* __restrict__ d4,
                            ushort4* __restrict__ xb, int n4x) {
  int i = blockIdx.x * blockDim.x + threadIdx.x;
  if (i >= n4x) return;
  int col4 = i & 1023;                 // 1024 float4 per x-row
  float4 v = x[i];
  float4 dd = d4[col4];
  ushort4 o;
  o.x = f2bf(v.x * rcp_hw(dd.x)); o.y = f2bf(v.y * rcp_hw(dd.y));
  o.z = f2bf(v.z * rcp_hw(dd.z)); o.w = f2bf(v.w * rcp_hw(dd.w));
  xb[i] = o;
}

// ---------------- kernel 3: GEMM 128x128, TK=64, XOR-swizzled LDS, split-K=4 ----------------
// LDS granule g of row r holds global granule (g ^ (r&7)); staging lane-contiguous,
// fragment ds_read_b128 conflict-free (verified R5: SQ_LDS_BANK_CONFLICT = 0).
#define TM 128
#define TN 128
#define TK 64
#define SPLITK 4

__launch_bounds__(256, 4)
__global__ void gemm_bt_kernel(const u16* __restrict__ A, const u16* __restrict__ BT,
                               float* __restrict__ C, int M, int N, int K) {
  __shared__ u16 As[TM * TK];  // 16 KB
  __shared__ u16 Bs[TN * TK];  // 16 KB

  const int tid = threadIdx.x;
  const int lane = tid & 63, w = tid >> 6;
  const int wm = w >> 1, wn = w & 1;           // 2x2 wave grid, 64x64 per wave
  const int m0 = blockIdx.x * TM, n0 = blockIdx.y * TN;
  const int quad = lane >> 4, r16 = lane & 15;
  const int srow = lane >> 3;                  // staging: row within 8-row chunk
  const int sg = (lane & 7) ^ srow;            // staging: swizzled 16B granule in row

  const int kz = blockIdx.z;
  const int Kq = K / SPLITK;                   // 1024
  const u16* Ak = A + (size_t)kz * Kq;
  const u16* Bk = BT + (size_t)kz * Kq;

  f32x4 acc[4][4] = {};

  for (int kt = 0; kt < Kq; kt += TK) {
    __syncthreads();
#pragma unroll
    for (int c = 0; c < 4; ++c) {
      int chunk = w * 4 + c;                   // 0..15, 8 rows x 64k each (1 KB)
      gld_lds16(Ak + (size_t)(m0 + chunk * 8 + srow) * K + kt + sg * 8, (char*)As + chunk * 1024);
      gld_lds16(Bk + (size_t)(n0 + chunk * 8 + srow) * K + kt + sg * 8, (char*)Bs + chunk * 1024);
    }
    __syncthreads();

#pragma unroll
    for (int ss = 0; ss < 2; ++ss) {           // two K=32 sub-steps per staged TK=64
      bf16x8 aF[4], bF[4];
#pragma unroll
      for (int mi = 0; mi < 4; ++mi) {
        int row = wm * 64 + mi * 16 + r16;
        aF[mi] = *(const bf16x8*)((const char*)As + row * 128 + (((ss * 4 + quad) ^ (row & 7)) * 16));
      }
#pragma unroll
      for (int ni = 0; ni < 4; ++ni) {
        int row = wn * 64 + ni * 16 + r16;
        bF[ni] = *(const bf16x8*)((const char*)Bs + row * 128 + (((ss * 4 + quad) ^ (row & 7)) * 16));
      }
#pragma unroll
      for (int mi = 0; mi < 4; ++mi)
#pragma unroll
        for (int ni = 0; ni < 4; ++ni)
          acc[mi][ni] = __builtin_amdgcn_mfma_f32_16x16x32_bf16(aF[mi], bF[ni], acc[mi][ni], 0, 0, 0);
    }
  }

  // epilogue: C/D layout col = lane&15, row = quad*4 + reg; accumulate split-K partials
#pragma unroll
  for (int mi = 0; mi < 4; ++mi)
#pragma unroll
    for (int ni = 0; ni < 4; ++ni)
#pragma unroll
      for (int r = 0; r < 4; ++r) {
        int row = m0 + wm * 64 + mi * 16 + quad * 4 + r;
        int col = n0 + wn * 64 + ni * 16 + r16;
        atomicAdd(&C[(size_t)row * N + col], acc[mi][ni][r]);
      }
}

extern "C" void kernel_launch(void* const* d_in, const int* in_sizes, int n_in,
                              void* d_out, int out_size, void* d_ws, size_t ws_size,
                              hipStream_t stream) {
  const int M = 4096, K = 4096, N = 1024;  // B, IN, OUT
  const float* x = (const float*)d_in[0];
  const float* W = (const float*)d_in[1];
  const float* U = (const float*)d_in[2];
  const float* Tp = (const float*)d_in[3];
  float* out = (float*)d_out;

  char* ws = (char*)d_ws;
  u16* xb = (u16*)ws;                                          // 32 MB
  u16* bt = (u16*)(ws + (size_t)M * K * 2);                    // 8 MB
  float* dsum = (float*)(ws + (size_t)M * K * 2 + (size_t)N * K * 2);  // 16 KB

  hipMemsetAsync(dsum, 0, K * sizeof(float), stream);
  trans_exp_kernel<<<dim3(K / 64, N / 64), 256, 0, stream>>>(W, U, Tp, bt, dsum, (float4*)out);
  cast_kernel<<<dim3(M * K / 4 / 256), 256, 0, stream>>>((const float4*)x, (const float4*)dsum,
                                                         (ushort4*)xb, M * K / 4);
  gemm_bt_kernel<<<dim3(M / TM, N / TN, SPLITK), 256, 0, stream>>>(xb, bt, out, M, N, K);
}